// Round 15
// baseline (331.531 us; speedup 1.0000x reference)
//
#include <hip/hip_runtime.h>
#include <hip/hip_bf16.h>

// Problem constants: B=8, N=1024, D_MODEL=512, H=8, HD=64
#define SCALE_ 0.125f
#define LN_EPS_ 1e-5f

typedef __attribute__((ext_vector_type(8))) short bf16x8;
typedef __attribute__((ext_vector_type(4))) float f32x4;

__device__ __forceinline__ ushort f2b(float f) {
  union { float f; unsigned u; } x; x.f = f;
  unsigned r = x.u + 0x7FFFu + ((x.u >> 16) & 1u);  // RNE
  return (ushort)(r >> 16);
}
__device__ __forceinline__ float b2f(short s) {
  union { float f; unsigned u; } x; x.u = ((unsigned)(ushort)s) << 16; return x.f;
}
__device__ __forceinline__ unsigned cvtpk(float lo, float hi) {
  union { __hip_bfloat162 h; unsigned u; } x;
  x.h = __float22bfloat162_rn(make_float2(lo, hi));
  return x.u;
}

__device__ __forceinline__ f32x4 mfma16(bf16x8 a, bf16x8 b, f32x4 c) {
  return __builtin_amdgcn_mfma_f32_16x16x32_bf16(a, b, c, 0, 0, 0);
}

// LDS-only barrier: does NOT drain vmcnt (global stores/loads stay in flight).
__device__ __forceinline__ void bar_lds() {
  asm volatile("s_waitcnt lgkmcnt(0)\n\ts_barrier" ::: "memory");
  __builtin_amdgcn_sched_barrier(0);
}

// ---------------- K0: f32 [R][C] -> bf16 [C][R] (transpose-cast for weights)
__global__ __launch_bounds__(256) void cast_transpose(const float* __restrict__ src,
                                                      ushort* __restrict__ dst,
                                                      int R, int C) {
  __shared__ ushort t[64][65];
  const int tid = threadIdx.x;
  const int c0 = blockIdx.x * 64, r0 = blockIdx.y * 64;
  const int lr = tid >> 2, lc = (tid & 3) * 16;
#pragma unroll
  for (int u = 0; u < 4; ++u) {
    float4 v = *(const float4*)&src[(size_t)(r0 + lr) * C + c0 + lc + u * 4];
    t[lc + u * 4 + 0][lr] = f2b(v.x);
    t[lc + u * 4 + 1][lr] = f2b(v.y);
    t[lc + u * 4 + 2][lr] = f2b(v.z);
    t[lc + u * 4 + 3][lr] = f2b(v.w);
  }
  __syncthreads();
#pragma unroll
  for (int u = 0; u < 2; ++u) {
    bf16x8 o;
#pragma unroll
    for (int e = 0; e < 8; ++e) o[e] = (short)t[lr][lc + u * 8 + e];
    *(bf16x8*)&dst[(size_t)(c0 + lr) * R + r0 + lc + u * 8] = o;
  }
}

// ---------------- K1: qkv = x @ W_qkv + b. 128x128 tile, fused f32->bf16 cast of x.
// Outputs: q, k in (b,h,i,d) bf16; v TRANSPOSED as vt (b,h,d,i) bf16.
__global__ __launch_bounds__(256) void qkv_mfma(const float* __restrict__ x,
                                                const ushort* __restrict__ Wt,
                                                const float* __restrict__ bias,
                                                ushort* __restrict__ q,
                                                ushort* __restrict__ k,
                                                ushort* __restrict__ vt) {
  __shared__ ushort A[128][40];
  __shared__ ushort Bs[128][40];
  const int tid = threadIdx.x;
  const int n0 = blockIdx.x * 128;
  const int m0 = blockIdx.y * 128;
  const int lane = tid & 63, wid = tid >> 6;
  const int wr = wid >> 1, wc = wid & 1;
  const int lr = lane & 15, g4 = lane >> 4;
  const int sr = tid >> 1, sco = (tid & 1) * 16;
  f32x4 acc[4][4] = {};
  for (int k0 = 0; k0 < 512; k0 += 32) {
    {
      const float4* xs = (const float4*)&x[(size_t)(m0 + sr) * 512 + k0 + sco];
      float4 v0 = xs[0], v1 = xs[1], v2 = xs[2], v3 = xs[3];
      bf16x8 p0, p1;
      p0[0] = (short)f2b(v0.x); p0[1] = (short)f2b(v0.y);
      p0[2] = (short)f2b(v0.z); p0[3] = (short)f2b(v0.w);
      p0[4] = (short)f2b(v1.x); p0[5] = (short)f2b(v1.y);
      p0[6] = (short)f2b(v1.z); p0[7] = (short)f2b(v1.w);
      p1[0] = (short)f2b(v2.x); p1[1] = (short)f2b(v2.y);
      p1[2] = (short)f2b(v2.z); p1[3] = (short)f2b(v2.w);
      p1[4] = (short)f2b(v3.x); p1[5] = (short)f2b(v3.y);
      p1[6] = (short)f2b(v3.z); p1[7] = (short)f2b(v3.w);
      *(bf16x8*)&A[sr][sco] = p0;
      *(bf16x8*)&A[sr][sco + 8] = p1;
    }
    {
      const bf16x8* wp = (const bf16x8*)&Wt[(size_t)(n0 + sr) * 512 + k0 + sco];
      *(bf16x8*)&Bs[sr][sco] = wp[0];
      *(bf16x8*)&Bs[sr][sco + 8] = wp[1];
    }
    __syncthreads();
    bf16x8 af[4], bf[4];
#pragma unroll
    for (int mr = 0; mr < 4; ++mr) af[mr] = *(bf16x8*)&A[wr * 64 + mr * 16 + lr][g4 * 8];
#pragma unroll
    for (int nr = 0; nr < 4; ++nr) bf[nr] = *(bf16x8*)&Bs[wc * 64 + nr * 16 + lr][g4 * 8];
#pragma unroll
    for (int mr = 0; mr < 4; ++mr)
#pragma unroll
      for (int nr = 0; nr < 4; ++nr) acc[mr][nr] = mfma16(af[mr], bf[nr], acc[mr][nr]);
    __syncthreads();
  }
  const int part = n0 >> 9;
#pragma unroll
  for (int mr = 0; mr < 4; ++mr)
#pragma unroll
    for (int nr = 0; nr < 4; ++nr) {
      const int n = n0 + wc * 64 + nr * 16 + lr;
      const int h = (n & 511) >> 6, d = n & 63;
      const float bb = bias[n];
#pragma unroll
      for (int r = 0; r < 4; ++r) {
        int token = m0 + wr * 64 + mr * 16 + g4 * 4 + r;
        int bi = token >> 10, ii = token & 1023;
        ushort valb = f2b(acc[mr][nr][r] + bb);
        if (part == 0)
          q[(((size_t)(bi * 8 + h) * 1024 + ii) * 64) + d] = valb;
        else if (part == 1)
          k[(((size_t)(bi * 8 + h) * 1024 + ii) * 64) + d] = valb;
        else
          vt[((size_t)(bi * 8 + h) * 64 + d) * 1024 + ii] = valb;
      }
    }
}

// ---------------- K2a: softmax denominators. 2048 x 1-wave blocks, no barriers,
// high occupancy. S^T: mfma(K,Q), psum over j rows. Needed BEFORE the j-split
// phase-1 kernel (each phase-1 block sees only half the j range).
__global__ __launch_bounds__(64) void denoms(const ushort* __restrict__ q,
                                             const ushort* __restrict__ k,
                                             float* __restrict__ invg) {
  const int bid = blockIdx.x;
  const int obid = ((bid & 7) << 8) + (bid >> 3);  // XCD x <- b = x
  const int bh = obid >> 5;
  const int it = obid & 31;
  const int lane = threadIdx.x;
  const int lr = lane & 15, g4 = lane >> 4;
  const ushort* qh = q + ((size_t)bh * 1024 + it * 32) * 64;
  const ushort* kh = k + (size_t)bh * 65536;

  bf16x8 qf[2][2];
#pragma unroll
  for (int ir = 0; ir < 2; ++ir)
#pragma unroll
    for (int ks = 0; ks < 2; ++ks)
      qf[ir][ks] = *(const bf16x8*)&qh[(size_t)(ir * 16 + lr) * 64 + ks * 32 + g4 * 8];

  float psum[2] = {0.f, 0.f};
  bf16x8 kc[4], kn[4];
#pragma unroll
  for (int jr = 0; jr < 2; ++jr)
#pragma unroll
    for (int ks = 0; ks < 2; ++ks)
      kc[jr * 2 + ks] = *(const bf16x8*)&kh[(size_t)(jr * 16 + lr) * 64 + ks * 32 + g4 * 8];
  for (int jt = 0; jt < 32; ++jt) {
    const int j0n = ((jt + 1) & 31) * 32;
#pragma unroll
    for (int jr = 0; jr < 2; ++jr)
#pragma unroll
      for (int ks = 0; ks < 2; ++ks)
        kn[jr * 2 + ks] =
            *(const bf16x8*)&kh[(size_t)(j0n + jr * 16 + lr) * 64 + ks * 32 + g4 * 8];
    f32x4 sa[2][2] = {};  // [jr][ir]
#pragma unroll
    for (int jr = 0; jr < 2; ++jr)
#pragma unroll
      for (int ir = 0; ir < 2; ++ir) {
        sa[jr][ir] = mfma16(kc[jr * 2 + 0], qf[ir][0], sa[jr][ir]);
        sa[jr][ir] = mfma16(kc[jr * 2 + 1], qf[ir][1], sa[jr][ir]);
      }
#pragma unroll
    for (int jr = 0; jr < 2; ++jr)
#pragma unroll
      for (int ir = 0; ir < 2; ++ir)
#pragma unroll
        for (int r = 0; r < 4; ++r) psum[ir] += __expf(sa[jr][ir][r] * SCALE_);
#pragma unroll
    for (int i = 0; i < 4; ++i) kc[i] = kn[i];
  }
#pragma unroll
  for (int ir = 0; ir < 2; ++ir) {
    float s = psum[ir];
    s += __shfl_xor(s, 16);
    s += __shfl_xor(s, 32);
    psum[ir] = s;
  }
  if (lane < 16) {
    invg[(size_t)bh * 1024 + it * 32 + lr] = 1.0f / psum[0];
    invg[(size_t)bh * 1024 + it * 32 + 16 + lr] = 1.0f / psum[1];
  }
}

// ---------------- K2b (fused phase 1): QBLK=64, 16 waves (wave = (head, row-half)),
// j-split in 2 halves -> 256 blocks x 16 jt iterations (HALF the barrier-phase
// count of QBLK=32) at 4 waves/SIMD. Per-wave per-iteration work identical to
// the QBLK=32 version (32 rows). VGPR must fit 128 (16 waves/CU): no K dbuf,
// mix accumulates over heads (low peak live state).
__global__ __launch_bounds__(1024) void attn_fused(const ushort* __restrict__ q,
                                                   const ushort* __restrict__ k,
                                                   const ushort* __restrict__ vt,
                                                   const float* __restrict__ rw,
                                                   const float* __restrict__ ln_g,
                                                   const float* __restrict__ ln_b,
                                                   const float* __restrict__ invg,
                                                   float* __restrict__ attn,
                                                   ushort* __restrict__ pv0,
                                                   ushort* __restrict__ pv1) {
  __shared__ float PM[8][64][36];  // 73728 B
  __shared__ float wsh[64];
  __shared__ float gsh[8], bsh[8];

  const int tid = threadIdx.x;
  const int lane = tid & 63;
  const int h = (tid >> 6) & 7;    // head
  const int rh = tid >> 9;         // row-half (0/1)
  // bijective swizzle: b == XCD
  const int obid = ((blockIdx.x & 7) << 5) + (blockIdx.x >> 3);
  const int b = obid >> 5;
  const int rem = obid & 31;
  const int i0 = (rem >> 1) * 64;
  const int jh = rem & 1;
  const int jbase = jh * 512;
  const int lr = lane & 15, g4 = lane >> 4;

  const int bh = b * 8 + h;
  const ushort* qh = q + ((size_t)bh * 1024 + i0 + rh * 32) * 64;
  const ushort* kh = k + (size_t)bh * 65536;
  const ushort* vth = vt + (size_t)bh * 65536;

  if (tid < 64) wsh[tid] = rw[tid];
  if (tid < 8) { gsh[tid] = ln_g[tid]; bsh[tid] = ln_b[tid]; }

  // Q fragments (B-operand: col = i, k-slice d); wave's rows = rh*32 + ir*16 + lr
  bf16x8 qf[2][2];
#pragma unroll
  for (int ir = 0; ir < 2; ++ir)
#pragma unroll
    for (int ks = 0; ks < 2; ++ks)
      qf[ir][ks] = *(const bf16x8*)&qh[(size_t)(ir * 16 + lr) * 64 + ks * 32 + g4 * 8];

  // denominators (global pass, L2-hot)
  float inv_[2];
#pragma unroll
  for (int ir = 0; ir < 2; ++ir)
    inv_[ir] = invg[(size_t)bh * 1024 + i0 + rh * 32 + ir * 16 + lr];

  f32x4 oaccT[4][2] = {};  // [dr][ic]: O^T partial for this j-half
  const int pair = tid & 1, chunk = tid >> 1;       // chunk 0..511
  const int m_ii = chunk >> 3;                      // 0..63
  const int m_jj = (chunk & 7) * 4;
  const int k2base = pair * 4;

  for (int jt = 0; jt < 16; ++jt) {
    const int j0 = jbase + jt * 32;

    // K fragments (A-operand rows j), L2-resident; no dbuf (VGPR budget)
    bf16x8 kc[4];
#pragma unroll
    for (int jr = 0; jr < 2; ++jr)
#pragma unroll
      for (int ks = 0; ks < 2; ++ks)
        kc[jr * 2 + ks] =
            *(const bf16x8*)&kh[(size_t)(j0 + jr * 16 + lr) * 64 + ks * 32 + g4 * 8];

    // S^T recompute; P = exp*inv -> PM[h][row][j], 4 consecutive j -> b128
    f32x4 sa[2][2] = {};  // [jr][ir]
#pragma unroll
    for (int jr = 0; jr < 2; ++jr)
#pragma unroll
      for (int ir = 0; ir < 2; ++ir) {
        sa[jr][ir] = mfma16(kc[jr * 2 + 0], qf[ir][0], sa[jr][ir]);
        sa[jr][ir] = mfma16(kc[jr * 2 + 1], qf[ir][1], sa[jr][ir]);
      }
#pragma unroll
    for (int jr = 0; jr < 2; ++jr)
#pragma unroll
      for (int ir = 0; ir < 2; ++ir) {
        f32x4 pw;
#pragma unroll
        for (int r = 0; r < 4; ++r) pw[r] = __expf(sa[jr][ir][r] * SCALE_) * inv_[ir];
        *(f32x4*)&PM[h][rh * 32 + ir * 16 + lr][jr * 16 + g4 * 4] = pw;
      }

    // V loads for this iteration (pre-B1, consumed post-B2)
    bf16x8 vc[4];
#pragma unroll
    for (int dr = 0; dr < 4; ++dr)
      vc[dr] = *(const bf16x8*)&vth[(size_t)(dr * 16 + lr) * 1024 + j0 + g4 * 8];

    bar_lds();  // B1: all heads' P visible

    // mix + LN: thread owns (m_ii, m_jj..+3, 4 heads); accumulate over h2
    // to keep peak register pressure low (16-wave VGPR budget).
    float mixed[4][4] = {};
#pragma unroll
    for (int h2 = 0; h2 < 8; ++h2) {
      float4 p = *(const float4*)&PM[h2][m_ii][m_jj];
#pragma unroll
      for (int k2l = 0; k2l < 4; ++k2l) {
        float w = wsh[h2 * 8 + k2base + k2l];
        mixed[k2l][0] += p.x * w; mixed[k2l][1] += p.y * w;
        mixed[k2l][2] += p.z * w; mixed[k2l][3] += p.w * w;
      }
    }
    float mu[4], rs_[4];
#pragma unroll
    for (int e = 0; e < 4; ++e) {
      float mp = mixed[0][e] + mixed[1][e] + mixed[2][e] + mixed[3][e];
      mu[e] = (mp + __shfl_xor(mp, 1)) * 0.125f;
    }
#pragma unroll
    for (int e = 0; e < 4; ++e) {
      float vp = 0.f;
#pragma unroll
      for (int k2l = 0; k2l < 4; ++k2l) {
        float d = mixed[k2l][e] - mu[e];
        vp += d * d;
      }
      float var = (vp + __shfl_xor(vp, 1)) * 0.125f;
      rs_[e] = rsqrtf(var + LN_EPS_);
    }
#pragma unroll
    for (int k2l = 0; k2l < 4; ++k2l) {
      int k2 = k2base + k2l;
      float g = gsh[k2], be = bsh[k2];
      f32x4 o;
      o[0] = (mixed[k2l][0] - mu[0]) * rs_[0] * g + be;
      o[1] = (mixed[k2l][1] - mu[1]) * rs_[1] * g + be;
      o[2] = (mixed[k2l][2] - mu[2]) * rs_[2] * g + be;
      o[3] = (mixed[k2l][3] - mu[3]) * rs_[3] * g + be;
      *(f32x4*)&attn[((size_t)(b * 8 + k2) << 20) + ((size_t)(i0 + m_ii) << 10) +
                     j0 + m_jj] = o;
      *(f32x4*)&PM[k2][m_ii][m_jj] = o;  // in-place
    }

    bar_lds();  // B2: LN'd PM visible

    // PV swapped: O^T += V^T(A) @ P^T(B); own (head, row-half) rows
    bf16x8 pab[2];
#pragma unroll
    for (int ic = 0; ic < 2; ++ic) {
      const float* pr = &PM[h][rh * 32 + ic * 16 + lr][g4 * 8];
      float4 p0 = *(const float4*)&pr[0];
      float4 p1 = *(const float4*)&pr[4];
      union { bf16x8 v; unsigned u[4]; } pk;
      pk.u[0] = cvtpk(p0.x, p0.y);
      pk.u[1] = cvtpk(p0.z, p0.w);
      pk.u[2] = cvtpk(p1.x, p1.y);
      pk.u[3] = cvtpk(p1.z, p1.w);
      pab[ic] = pk.v;
    }
#pragma unroll
    for (int dr = 0; dr < 4; ++dr) {
      oaccT[dr][0] = mfma16(vc[dr], pab[0], oaccT[dr][0]);
      oaccT[dr][1] = mfma16(vc[dr], pab[1], oaccT[dr][1]);
    }
  }

  // write pv partial (bf16, (b,h,i,d)); rows rh*32 + ic*16 + lr
  ushort* po = (jh == 0 ? pv0 : pv1) + ((size_t)bh * 1024 + i0 + rh * 32) * 64;
#pragma unroll
  for (int ic = 0; ic < 2; ++ic)
#pragma unroll
    for (int dr = 0; dr < 4; ++dr) {
      union { ushort4 s; unsigned u[2]; } o;
      o.u[0] = cvtpk(oaccT[dr][ic][0], oaccT[dr][ic][1]);
      o.u[1] = cvtpk(oaccT[dr][ic][2], oaccT[dr][ic][3]);
      *(ushort4*)&po[(size_t)(ic * 16 + lr) * 64 + dr * 16 + g4 * 4] = o.s;
    }
}

// ---------------- K3: out = (pv0+pv1)(b,n,(h d)) @ W_out + b_out. 128x128 tile.
__global__ __launch_bounds__(256) void out_mfma(const ushort* __restrict__ pv0,
                                                const ushort* __restrict__ pv1,
                                                const ushort* __restrict__ Wt,
                                                const float* __restrict__ bias,
                                                float* __restrict__ out) {
  __shared__ ushort A[128][40];
  __shared__ ushort Bs[128][40];
  const int tid = threadIdx.x;
  const int n0 = blockIdx.x * 128;
  const int m0 = blockIdx.y * 128;
  const int lane = tid & 63, wid = tid >> 6;
  const int wr = wid >> 1, wc = wid & 1;
  const int lr = lane & 15, g4 = lane >> 4;
  const int sr = tid >> 1, sco = (tid & 1) * 16;
  f32x4 acc[4][4] = {};
  for (int k0 = 0; k0 < 512; k0 += 32) {
    {
      int token = m0 + sr;
      int bi = token >> 10, ii = token & 1023;
      int f = k0 + sco;
      int hh = f >> 6, d = f & 63;
      const size_t idx = (((size_t)(bi * 8 + hh)) * 1024 + ii) * 64 + d;
      bf16x8 a0 = *(const bf16x8*)&pv0[idx];
      bf16x8 a1 = *(const bf16x8*)&pv0[idx + 8];
      bf16x8 c0 = *(const bf16x8*)&pv1[idx];
      bf16x8 c1 = *(const bf16x8*)&pv1[idx + 8];
      bf16x8 r0, r1;
#pragma unroll
      for (int e = 0; e < 8; ++e) {
        r0[e] = (short)f2b(b2f(a0[e]) + b2f(c0[e]));
        r1[e] = (short)f2b(b2f(a1[e]) + b2f(c1[e]));
      }
      *(bf16x8*)&A[sr][sco] = r0;
      *(bf16x8*)&A[sr][sco + 8] = r1;
    }
    {
      const bf16x8* wp = (const bf16x8*)&Wt[(size_t)(n0 + sr) * 512 + k0 + sco];
      *(bf16x8*)&Bs[sr][sco] = wp[0];
      *(bf16x8*)&Bs[sr][sco + 8] = wp[1];
    }
    __syncthreads();
    bf16x8 af[4], bf[4];
#pragma unroll
    for (int mr = 0; mr < 4; ++mr) af[mr] = *(bf16x8*)&A[wr * 64 + mr * 16 + lr][g4 * 8];
#pragma unroll
    for (int nr = 0; nr < 4; ++nr) bf[nr] = *(bf16x8*)&Bs[wc * 64 + nr * 16 + lr][g4 * 8];
#pragma unroll
    for (int mr = 0; mr < 4; ++mr)
#pragma unroll
      for (int nr = 0; nr < 4; ++nr) acc[mr][nr] = mfma16(af[mr], bf[nr], acc[mr][nr]);
    __syncthreads();
  }
#pragma unroll
  for (int mr = 0; mr < 4; ++mr)
#pragma unroll
    for (int nr = 0; nr < 4; ++nr) {
      const int n = n0 + wc * 64 + nr * 16 + lr;
      const float bb = bias[n];
#pragma unroll
      for (int r = 0; r < 4; ++r) {
        int token = m0 + wr * 64 + mr * 16 + g4 * 4 + r;
        out[(size_t)token * 512 + n] = acc[mr][nr][r] + bb;
      }
    }
}

extern "C" void kernel_launch(void* const* d_in, const int* in_sizes, int n_in,
                              void* d_out, int out_size, void* d_ws, size_t ws_size,
                              hipStream_t stream) {
  const float* x    = (const float*)d_in[0];
  const float* Wqkv = (const float*)d_in[1];
  const float* bqkv = (const float*)d_in[2];
  const float* rw   = (const float*)d_in[3];
  const float* lng  = (const float*)d_in[4];
  const float* lnb  = (const float*)d_in[5];
  const float* Wout = (const float*)d_in[6];
  const float* bout = (const float*)d_in[7];

  float* out  = (float*)d_out;
  float* attn = (float*)d_out + 4194304;

  // ws: q [0,8M), k [8,16M), vt [16,24M), pv0 [24,32M), pv1 [32,40M),
  //     Wqkvt [40,41.5M), Woutt [41.5,42M), invg [42,42.25M)
  char* wsb = (char*)d_ws;
  ushort* q     = (ushort*)(wsb);
  ushort* k     = (ushort*)(wsb + (8u << 20));
  ushort* vt    = (ushort*)(wsb + (16u << 20));
  ushort* pv0   = (ushort*)(wsb + (24u << 20));
  ushort* pv1   = (ushort*)(wsb + (32u << 20));
  ushort* Wqkvt = (ushort*)(wsb + (40u << 20));
  ushort* Woutt = (ushort*)(wsb + (41u << 20) + (1u << 19));
  float*  invg  = (float*)(wsb + (42u << 20));

  cast_transpose<<<dim3(24, 8), 256, 0, stream>>>(Wqkv, Wqkvt, 512, 1536);
  cast_transpose<<<dim3(8, 8), 256, 0, stream>>>(Wout, Woutt, 512, 512);

  qkv_mfma<<<dim3(12, 64), 256, 0, stream>>>(x, Wqkvt, bqkv, q, k, vt);
  denoms<<<dim3(2048), 64, 0, stream>>>(q, k, invg);
  attn_fused<<<dim3(256), 1024, 0, stream>>>(q, k, vt, rw, lng, lnb, invg, attn, pv0, pv1);
  out_mfma<<<dim3(4, 64), 256, 0, stream>>>(pv0, pv1, Woutt, bout, out);
}

// Round 16
// 227.212 us; speedup vs baseline: 1.4591x; 1.4591x over previous
//
#include <hip/hip_runtime.h>
#include <hip/hip_bf16.h>

// Problem constants: B=8, N=1024, D_MODEL=512, H=8, HD=64
#define SCALE_ 0.125f
#define LN_EPS_ 1e-5f

typedef __attribute__((ext_vector_type(8))) short bf16x8;
typedef __attribute__((ext_vector_type(4))) float f32x4;

__device__ __forceinline__ ushort f2b(float f) {
  union { float f; unsigned u; } x; x.f = f;
  unsigned r = x.u + 0x7FFFu + ((x.u >> 16) & 1u);  // RNE
  return (ushort)(r >> 16);
}
__device__ __forceinline__ unsigned cvtpk(float lo, float hi) {
  union { __hip_bfloat162 h; unsigned u; } x;
  x.h = __float22bfloat162_rn(make_float2(lo, hi));
  return x.u;
}

__device__ __forceinline__ f32x4 mfma16(bf16x8 a, bf16x8 b, f32x4 c) {
  return __builtin_amdgcn_mfma_f32_16x16x32_bf16(a, b, c, 0, 0, 0);
}

// LDS-only barrier: does NOT drain vmcnt (global stores/loads stay in flight).
__device__ __forceinline__ void bar_lds() {
  asm volatile("s_waitcnt lgkmcnt(0)\n\ts_barrier" ::: "memory");
  __builtin_amdgcn_sched_barrier(0);
}

// ---------------- K0: f32 [R][C] -> bf16 [C][R] (transpose-cast for weights)
__global__ __launch_bounds__(256) void cast_transpose(const float* __restrict__ src,
                                                      ushort* __restrict__ dst,
                                                      int R, int C) {
  __shared__ ushort t[64][65];
  const int tid = threadIdx.x;
  const int c0 = blockIdx.x * 64, r0 = blockIdx.y * 64;
  const int lr = tid >> 2, lc = (tid & 3) * 16;
#pragma unroll
  for (int u = 0; u < 4; ++u) {
    float4 v = *(const float4*)&src[(size_t)(r0 + lr) * C + c0 + lc + u * 4];
    t[lc + u * 4 + 0][lr] = f2b(v.x);
    t[lc + u * 4 + 1][lr] = f2b(v.y);
    t[lc + u * 4 + 2][lr] = f2b(v.z);
    t[lc + u * 4 + 3][lr] = f2b(v.w);
  }
  __syncthreads();
#pragma unroll
  for (int u = 0; u < 2; ++u) {
    bf16x8 o;
#pragma unroll
    for (int e = 0; e < 8; ++e) o[e] = (short)t[lr][lc + u * 8 + e];
    *(bf16x8*)&dst[(size_t)(c0 + lr) * R + r0 + lc + u * 8] = o;
  }
}

// ---------------- K1: qkv = x @ W_qkv + b. 128x128 tile, fused f32->bf16 cast of x.
// Outputs: q, k in (b,h,i,d) bf16; v TRANSPOSED as vt (b,h,d,i) bf16.
__global__ __launch_bounds__(256) void qkv_mfma(const float* __restrict__ x,
                                                const ushort* __restrict__ Wt,
                                                const float* __restrict__ bias,
                                                ushort* __restrict__ q,
                                                ushort* __restrict__ k,
                                                ushort* __restrict__ vt) {
  __shared__ ushort A[128][40];
  __shared__ ushort Bs[128][40];
  const int tid = threadIdx.x;
  const int n0 = blockIdx.x * 128;
  const int m0 = blockIdx.y * 128;
  const int lane = tid & 63, wid = tid >> 6;
  const int wr = wid >> 1, wc = wid & 1;
  const int lr = lane & 15, g4 = lane >> 4;
  const int sr = tid >> 1, sco = (tid & 1) * 16;
  f32x4 acc[4][4] = {};
  for (int k0 = 0; k0 < 512; k0 += 32) {
    {
      const float4* xs = (const float4*)&x[(size_t)(m0 + sr) * 512 + k0 + sco];
      float4 v0 = xs[0], v1 = xs[1], v2 = xs[2], v3 = xs[3];
      bf16x8 p0, p1;
      p0[0] = (short)f2b(v0.x); p0[1] = (short)f2b(v0.y);
      p0[2] = (short)f2b(v0.z); p0[3] = (short)f2b(v0.w);
      p0[4] = (short)f2b(v1.x); p0[5] = (short)f2b(v1.y);
      p0[6] = (short)f2b(v1.z); p0[7] = (short)f2b(v1.w);
      p1[0] = (short)f2b(v2.x); p1[1] = (short)f2b(v2.y);
      p1[2] = (short)f2b(v2.z); p1[3] = (short)f2b(v2.w);
      p1[4] = (short)f2b(v3.x); p1[5] = (short)f2b(v3.y);
      p1[6] = (short)f2b(v3.z); p1[7] = (short)f2b(v3.w);
      *(bf16x8*)&A[sr][sco] = p0;
      *(bf16x8*)&A[sr][sco + 8] = p1;
    }
    {
      const bf16x8* wp = (const bf16x8*)&Wt[(size_t)(n0 + sr) * 512 + k0 + sco];
      *(bf16x8*)&Bs[sr][sco] = wp[0];
      *(bf16x8*)&Bs[sr][sco + 8] = wp[1];
    }
    __syncthreads();
    bf16x8 af[4], bf[4];
#pragma unroll
    for (int mr = 0; mr < 4; ++mr) af[mr] = *(bf16x8*)&A[wr * 64 + mr * 16 + lr][g4 * 8];
#pragma unroll
    for (int nr = 0; nr < 4; ++nr) bf[nr] = *(bf16x8*)&Bs[wc * 64 + nr * 16 + lr][g4 * 8];
#pragma unroll
    for (int mr = 0; mr < 4; ++mr)
#pragma unroll
      for (int nr = 0; nr < 4; ++nr) acc[mr][nr] = mfma16(af[mr], bf[nr], acc[mr][nr]);
    __syncthreads();
  }
  const int part = n0 >> 9;
#pragma unroll
  for (int mr = 0; mr < 4; ++mr)
#pragma unroll
    for (int nr = 0; nr < 4; ++nr) {
      const int n = n0 + wc * 64 + nr * 16 + lr;
      const int h = (n & 511) >> 6, d = n & 63;
      const float bb = bias[n];
#pragma unroll
      for (int r = 0; r < 4; ++r) {
        int token = m0 + wr * 64 + mr * 16 + g4 * 4 + r;
        int bi = token >> 10, ii = token & 1023;
        ushort valb = f2b(acc[mr][nr][r] + bb);
        if (part == 0)
          q[(((size_t)(bi * 8 + h) * 1024 + ii) * 64) + d] = valb;
        else if (part == 1)
          k[(((size_t)(bi * 8 + h) * 1024 + ii) * 64) + d] = valb;
        else
          vt[((size_t)(bi * 8 + h) * 64 + d) * 1024 + ii] = valb;
      }
    }
}

// ---------------- K2a: softmax denominators. 2048 x 1-wave blocks, no barriers.
__global__ __launch_bounds__(64) void denoms(const ushort* __restrict__ q,
                                             const ushort* __restrict__ k,
                                             float* __restrict__ invg) {
  const int bid = blockIdx.x;
  const int obid = ((bid & 7) << 8) + (bid >> 3);  // XCD x <- b = x
  const int bh = obid >> 5;
  const int it = obid & 31;
  const int lane = threadIdx.x;
  const int lr = lane & 15, g4 = lane >> 4;
  const ushort* qh = q + ((size_t)bh * 1024 + it * 32) * 64;
  const ushort* kh = k + (size_t)bh * 65536;

  bf16x8 qf[2][2];
#pragma unroll
  for (int ir = 0; ir < 2; ++ir)
#pragma unroll
    for (int ks = 0; ks < 2; ++ks)
      qf[ir][ks] = *(const bf16x8*)&qh[(size_t)(ir * 16 + lr) * 64 + ks * 32 + g4 * 8];

  float psum[2] = {0.f, 0.f};
  bf16x8 kc[4], kn[4];
#pragma unroll
  for (int jr = 0; jr < 2; ++jr)
#pragma unroll
    for (int ks = 0; ks < 2; ++ks)
      kc[jr * 2 + ks] = *(const bf16x8*)&kh[(size_t)(jr * 16 + lr) * 64 + ks * 32 + g4 * 8];
  for (int jt = 0; jt < 32; ++jt) {
    const int j0n = ((jt + 1) & 31) * 32;
#pragma unroll
    for (int jr = 0; jr < 2; ++jr)
#pragma unroll
      for (int ks = 0; ks < 2; ++ks)
        kn[jr * 2 + ks] =
            *(const bf16x8*)&kh[(size_t)(j0n + jr * 16 + lr) * 64 + ks * 32 + g4 * 8];
    f32x4 sa[2][2] = {};  // [jr][ir]
#pragma unroll
    for (int jr = 0; jr < 2; ++jr)
#pragma unroll
      for (int ir = 0; ir < 2; ++ir) {
        sa[jr][ir] = mfma16(kc[jr * 2 + 0], qf[ir][0], sa[jr][ir]);
        sa[jr][ir] = mfma16(kc[jr * 2 + 1], qf[ir][1], sa[jr][ir]);
      }
#pragma unroll
    for (int jr = 0; jr < 2; ++jr)
#pragma unroll
      for (int ir = 0; ir < 2; ++ir)
#pragma unroll
        for (int r = 0; r < 4; ++r) psum[ir] += __expf(sa[jr][ir][r] * SCALE_);
#pragma unroll
    for (int i = 0; i < 4; ++i) kc[i] = kn[i];
  }
#pragma unroll
  for (int ir = 0; ir < 2; ++ir) {
    float s = psum[ir];
    s += __shfl_xor(s, 16);
    s += __shfl_xor(s, 32);
    psum[ir] = s;
  }
  if (lane < 16) {
    invg[(size_t)bh * 1024 + it * 32 + lr] = 1.0f / psum[0];
    invg[(size_t)bh * 1024 + it * 32 + 16 + lr] = 1.0f / psum[1];
  }
}

// ---------------- K2b (fused phase 1, producer-consumer): 768 threads =
// 8 COMPUTE waves (wave h = head h; S^T -> P -> mix -> LN -> PV; NO global
// stores) + 4 STORE waves (read LN'd PM after B2, own the attn store stream;
// their vmcnt queue is never waited on -> stores drain in background).
// PM double-buffered so stores of tile jt overlap compute of jt+1.
// QBLK=32, 256 blocks (1/CU, 12 waves = 3/SIMD), XCD-swizzled (b == XCD).
__global__ __launch_bounds__(768, 2) void attn_fused(const ushort* __restrict__ q,
                                                     const ushort* __restrict__ k,
                                                     const ushort* __restrict__ vt,
                                                     const float* __restrict__ rw,
                                                     const float* __restrict__ ln_g,
                                                     const float* __restrict__ ln_b,
                                                     const float* __restrict__ invg,
                                                     float* __restrict__ attn,
                                                     ushort* __restrict__ pv) {
  __shared__ float PM[2][8][32][36];  // 147456 B, double-buffered
  __shared__ float wsh[64];
  __shared__ float gsh[8], bsh[8];

  const int tid = threadIdx.x;
  const int lane = tid & 63;
  const int wid = tid >> 6;          // 0..11
  const bool is_compute = wid < 8;
  const int h = wid & 7;
  const int obid = ((blockIdx.x & 7) << 5) + (blockIdx.x >> 3);  // b == XCD
  const int i0 = (obid & 31) * 32;
  const int b = obid >> 5;
  const int lr = lane & 15, g4 = lane >> 4;

  const int bh = b * 8 + h;
  const ushort* kh = k + (size_t)bh * 65536;
  const ushort* vth = vt + (size_t)bh * 65536;

  if (tid < 64) wsh[tid] = rw[tid];
  if (tid < 8) { gsh[tid] = ln_g[tid]; bsh[tid] = ln_b[tid]; }

  // Compute-wave state
  bf16x8 qf[2][2];
  float inv_[2];
  if (is_compute) {
    const ushort* qh = q + ((size_t)bh * 1024 + i0) * 64;
#pragma unroll
    for (int ir = 0; ir < 2; ++ir)
#pragma unroll
      for (int ks = 0; ks < 2; ++ks)
        qf[ir][ks] = *(const bf16x8*)&qh[(size_t)(ir * 16 + lr) * 64 + ks * 32 + g4 * 8];
#pragma unroll
    for (int ir = 0; ir < 2; ++ir)
      inv_[ir] = invg[(size_t)bh * 1024 + i0 + ir * 16 + lr];
  }

  f32x4 oaccT[4][2] = {};  // [dr][ic]: O^T
  // mix ownership over 512 compute threads
  const int pair = tid & 1, chunk = tid >> 1;
  const int m_ii = (chunk >> 3) & 31, m_jj = (chunk & 7) * 4;
  const int k2base = pair * 4;
  // store-wave ownership (tid 512..767)
  const int st = tid - 512;
  const int s_ii = st >> 3, s_jj4 = (st & 7) * 4;

  for (int jt = 0; jt < 32; ++jt) {
    const int j0 = jt * 32;
    const int buf = jt & 1;
    bf16x8 vc[4];
    if (is_compute) {
      // K fragments (A-operand rows j)
      bf16x8 kc[4];
#pragma unroll
      for (int jr = 0; jr < 2; ++jr)
#pragma unroll
        for (int ks = 0; ks < 2; ++ks)
          kc[jr * 2 + ks] =
              *(const bf16x8*)&kh[(size_t)(j0 + jr * 16 + lr) * 64 + ks * 32 + g4 * 8];

      // S^T recompute; P = exp*inv -> PM[buf][h]
      f32x4 sa[2][2] = {};  // [jr][ir]
#pragma unroll
      for (int jr = 0; jr < 2; ++jr)
#pragma unroll
        for (int ir = 0; ir < 2; ++ir) {
          sa[jr][ir] = mfma16(kc[jr * 2 + 0], qf[ir][0], sa[jr][ir]);
          sa[jr][ir] = mfma16(kc[jr * 2 + 1], qf[ir][1], sa[jr][ir]);
        }
#pragma unroll
      for (int jr = 0; jr < 2; ++jr)
#pragma unroll
        for (int ir = 0; ir < 2; ++ir) {
          f32x4 pw;
#pragma unroll
          for (int r = 0; r < 4; ++r) pw[r] = __expf(sa[jr][ir][r] * SCALE_) * inv_[ir];
          *(f32x4*)&PM[buf][h][ir * 16 + lr][jr * 16 + g4 * 4] = pw;
        }
      // V loads for this iteration (pre-B1, consumed post-B2)
#pragma unroll
      for (int dr = 0; dr < 4; ++dr)
        vc[dr] = *(const bf16x8*)&vth[(size_t)(dr * 16 + lr) * 1024 + j0 + g4 * 8];
    }

    bar_lds();  // B1: all heads' P visible

    if (is_compute) {
      // mix + LN (float4, head-split across lane pairs), in-place PM update
      float4 ph[8];
#pragma unroll
      for (int h2 = 0; h2 < 8; ++h2) ph[h2] = *(const float4*)&PM[buf][h2][m_ii][m_jj];
      float mixed[4][4];
#pragma unroll
      for (int k2l = 0; k2l < 4; ++k2l) {
        float a0 = 0.f, a1 = 0.f, a2 = 0.f, a3 = 0.f;
#pragma unroll
        for (int h2 = 0; h2 < 8; ++h2) {
          float w = wsh[h2 * 8 + k2base + k2l];
          a0 += ph[h2].x * w; a1 += ph[h2].y * w;
          a2 += ph[h2].z * w; a3 += ph[h2].w * w;
        }
        mixed[k2l][0] = a0; mixed[k2l][1] = a1; mixed[k2l][2] = a2; mixed[k2l][3] = a3;
      }
      float mu[4], rs_[4];
#pragma unroll
      for (int e = 0; e < 4; ++e) {
        float mp = mixed[0][e] + mixed[1][e] + mixed[2][e] + mixed[3][e];
        mu[e] = (mp + __shfl_xor(mp, 1)) * 0.125f;
      }
#pragma unroll
      for (int e = 0; e < 4; ++e) {
        float vp = 0.f;
#pragma unroll
        for (int k2l = 0; k2l < 4; ++k2l) {
          float d = mixed[k2l][e] - mu[e];
          vp += d * d;
        }
        float var = (vp + __shfl_xor(vp, 1)) * 0.125f;
        rs_[e] = rsqrtf(var + LN_EPS_);
      }
#pragma unroll
      for (int k2l = 0; k2l < 4; ++k2l) {
        int k2 = k2base + k2l;
        float g = gsh[k2], be = bsh[k2];
        f32x4 o;
        o[0] = (mixed[k2l][0] - mu[0]) * rs_[0] * g + be;
        o[1] = (mixed[k2l][1] - mu[1]) * rs_[1] * g + be;
        o[2] = (mixed[k2l][2] - mu[2]) * rs_[2] * g + be;
        o[3] = (mixed[k2l][3] - mu[3]) * rs_[3] * g + be;
        *(f32x4*)&PM[buf][k2][m_ii][m_jj] = o;  // in-place (no global store here)
      }
    }

    bar_lds();  // B2: LN'd PM[buf] visible

    if (is_compute) {
      // PV swapped: O^T += V^T(A) @ P^T(B)
      bf16x8 pab[2];
#pragma unroll
      for (int ic = 0; ic < 2; ++ic) {
        const float* pr = &PM[buf][h][ic * 16 + lr][g4 * 8];
        float4 p0 = *(const float4*)&pr[0];
        float4 p1 = *(const float4*)&pr[4];
        union { bf16x8 v; unsigned u[4]; } pk;
        pk.u[0] = cvtpk(p0.x, p0.y);
        pk.u[1] = cvtpk(p0.z, p0.w);
        pk.u[2] = cvtpk(p1.x, p1.y);
        pk.u[3] = cvtpk(p1.z, p1.w);
        pab[ic] = pk.v;
      }
#pragma unroll
      for (int dr = 0; dr < 4; ++dr) {
        oaccT[dr][0] = mfma16(vc[dr], pab[0], oaccT[dr][0]);
        oaccT[dr][1] = mfma16(vc[dr], pab[1], oaccT[dr][1]);
      }
    } else {
      // STORE waves: stream LN'd PM[buf] to attn global. These stores live in
      // the store waves' vmcnt queues; no one waits on them -> background drain.
      // Window: B2(jt) .. B1(jt+1) guards reads vs S(jt+2) overwrite (dbuf).
#pragma unroll
      for (int k2 = 0; k2 < 8; ++k2) {
        f32x4 o = *(const f32x4*)&PM[buf][k2][s_ii][s_jj4];
        *(f32x4*)&attn[((size_t)(b * 8 + k2) << 20) + ((size_t)(i0 + s_ii) << 10) +
                       j0 + s_jj4] = o;
      }
    }
  }

  // write pv (bf16, (b,h,i,d))
  if (is_compute) {
    ushort* po = pv + ((size_t)bh * 1024 + i0) * 64;
#pragma unroll
    for (int ic = 0; ic < 2; ++ic)
#pragma unroll
      for (int dr = 0; dr < 4; ++dr) {
        union { ushort4 s; unsigned u[2]; } o;
        o.u[0] = cvtpk(oaccT[dr][ic][0], oaccT[dr][ic][1]);
        o.u[1] = cvtpk(oaccT[dr][ic][2], oaccT[dr][ic][3]);
        *(ushort4*)&po[(size_t)(ic * 16 + lr) * 64 + dr * 16 + g4 * 4] = o.s;
      }
  }
}

// ---------------- K3: out = pv(b,n,(h d)) @ W_out + b_out. 128x128 tile.
__global__ __launch_bounds__(256) void out_mfma(const ushort* __restrict__ pvb,
                                                const ushort* __restrict__ Wt,
                                                const float* __restrict__ bias,
                                                float* __restrict__ out) {
  __shared__ ushort A[128][40];
  __shared__ ushort Bs[128][40];
  const int tid = threadIdx.x;
  const int n0 = blockIdx.x * 128;
  const int m0 = blockIdx.y * 128;
  const int lane = tid & 63, wid = tid >> 6;
  const int wr = wid >> 1, wc = wid & 1;
  const int lr = lane & 15, g4 = lane >> 4;
  const int sr = tid >> 1, sco = (tid & 1) * 16;
  f32x4 acc[4][4] = {};
  for (int k0 = 0; k0 < 512; k0 += 32) {
    {
      int token = m0 + sr;
      int bi = token >> 10, ii = token & 1023;
      int f = k0 + sco;
      int hh = f >> 6, d = f & 63;
      const bf16x8* src =
          (const bf16x8*)&pvb[(((size_t)(bi * 8 + hh)) * 1024 + ii) * 64 + d];
      *(bf16x8*)&A[sr][sco] = src[0];
      *(bf16x8*)&A[sr][sco + 8] = src[1];
    }
    {
      const bf16x8* wp = (const bf16x8*)&Wt[(size_t)(n0 + sr) * 512 + k0 + sco];
      *(bf16x8*)&Bs[sr][sco] = wp[0];
      *(bf16x8*)&Bs[sr][sco + 8] = wp[1];
    }
    __syncthreads();
    bf16x8 af[4], bf[4];
#pragma unroll
    for (int mr = 0; mr < 4; ++mr) af[mr] = *(bf16x8*)&A[wr * 64 + mr * 16 + lr][g4 * 8];
#pragma unroll
    for (int nr = 0; nr < 4; ++nr) bf[nr] = *(bf16x8*)&Bs[wc * 64 + nr * 16 + lr][g4 * 8];
#pragma unroll
    for (int mr = 0; mr < 4; ++mr)
#pragma unroll
      for (int nr = 0; nr < 4; ++nr) acc[mr][nr] = mfma16(af[mr], bf[nr], acc[mr][nr]);
    __syncthreads();
  }
#pragma unroll
  for (int mr = 0; mr < 4; ++mr)
#pragma unroll
    for (int nr = 0; nr < 4; ++nr) {
      const int n = n0 + wc * 64 + nr * 16 + lr;
      const float bb = bias[n];
#pragma unroll
      for (int r = 0; r < 4; ++r) {
        int token = m0 + wr * 64 + mr * 16 + g4 * 4 + r;
        out[(size_t)token * 512 + n] = acc[mr][nr][r] + bb;
      }
    }
}

extern "C" void kernel_launch(void* const* d_in, const int* in_sizes, int n_in,
                              void* d_out, int out_size, void* d_ws, size_t ws_size,
                              hipStream_t stream) {
  const float* x    = (const float*)d_in[0];
  const float* Wqkv = (const float*)d_in[1];
  const float* bqkv = (const float*)d_in[2];
  const float* rw   = (const float*)d_in[3];
  const float* lng  = (const float*)d_in[4];
  const float* lnb  = (const float*)d_in[5];
  const float* Wout = (const float*)d_in[6];
  const float* bout = (const float*)d_in[7];

  float* out  = (float*)d_out;
  float* attn = (float*)d_out + 4194304;

  // ws: q [0,8M), k [8,16M), vt [16,24M), pvb [24,32M), Wqkvt [32,33.5M),
  //     Woutt [33.5,34M), invg [34,34.25M)
  char* wsb = (char*)d_ws;
  ushort* q     = (ushort*)(wsb);
  ushort* k     = (ushort*)(wsb + (8u << 20));
  ushort* vt    = (ushort*)(wsb + (16u << 20));
  ushort* pvb   = (ushort*)(wsb + (24u << 20));
  ushort* Wqkvt = (ushort*)(wsb + (32u << 20));
  ushort* Woutt = (ushort*)(wsb + (33u << 20) + (1u << 19));
  float*  invg  = (float*)(wsb + (34u << 20));

  cast_transpose<<<dim3(24, 8), 256, 0, stream>>>(Wqkv, Wqkvt, 512, 1536);
  cast_transpose<<<dim3(8, 8), 256, 0, stream>>>(Wout, Woutt, 512, 512);

  qkv_mfma<<<dim3(12, 64), 256, 0, stream>>>(x, Wqkvt, bqkv, q, k, vt);
  denoms<<<dim3(2048), 64, 0, stream>>>(q, k, invg);
  attn_fused<<<dim3(256), 768, 0, stream>>>(q, k, vt, rw, lng, lnb, invg, attn, pvb);
  out_mfma<<<dim3(4, 64), 256, 0, stream>>>(pvb, Woutt, bout, out);
}

// Round 17
// 170.635 us; speedup vs baseline: 1.9429x; 1.3316x over previous
//
#include <hip/hip_runtime.h>
#include <hip/hip_bf16.h>

// Problem constants: B=8, N=1024, D_MODEL=512, H=8, HD=64
#define SCALE_ 0.125f
#define LN_EPS_ 1e-5f

typedef __attribute__((ext_vector_type(8))) short bf16x8;
typedef __attribute__((ext_vector_type(4))) float f32x4;

__device__ __forceinline__ ushort f2b(float f) {
  union { float f; unsigned u; } x; x.f = f;
  unsigned r = x.u + 0x7FFFu + ((x.u >> 16) & 1u);  // RNE
  return (ushort)(r >> 16);
}
__device__ __forceinline__ unsigned cvtpk(float lo, float hi) {
  union { __hip_bfloat162 h; unsigned u; } x;
  x.h = __float22bfloat162_rn(make_float2(lo, hi));
  return x.u;
}

__device__ __forceinline__ f32x4 mfma16(bf16x8 a, bf16x8 b, f32x4 c) {
  return __builtin_amdgcn_mfma_f32_16x16x32_bf16(a, b, c, 0, 0, 0);
}

// LDS-only barrier: does NOT drain vmcnt (global stores/loads stay in flight).
__device__ __forceinline__ void bar_lds() {
  asm volatile("s_waitcnt lgkmcnt(0)\n\ts_barrier" ::: "memory");
  __builtin_amdgcn_sched_barrier(0);
}

// ---------------- K0 (merged): f32 [R][C] -> bf16 [C][R] for BOTH weights.
// blocks 0..191: Wqkv (512x1536, 24 c-tiles x 8 r-tiles); 192..255: Wout (512x512).
__global__ __launch_bounds__(256) void cast_transpose2(const float* __restrict__ srcA,
                                                       ushort* __restrict__ dstA,
                                                       const float* __restrict__ srcB,
                                                       ushort* __restrict__ dstB) {
  __shared__ ushort t[64][65];
  const int bid = blockIdx.x;
  const float* src;
  ushort* dst;
  int R, C, c0, r0;
  if (bid < 192) {
    src = srcA; dst = dstA; R = 512; C = 1536;
    c0 = (bid % 24) * 64; r0 = (bid / 24) * 64;
  } else {
    src = srcB; dst = dstB; R = 512; C = 512;
    int b2 = bid - 192;
    c0 = (b2 % 8) * 64; r0 = (b2 / 8) * 64;
  }
  const int tid = threadIdx.x;
  const int lr = tid >> 2, lc = (tid & 3) * 16;
#pragma unroll
  for (int u = 0; u < 4; ++u) {
    float4 v = *(const float4*)&src[(size_t)(r0 + lr) * C + c0 + lc + u * 4];
    t[lc + u * 4 + 0][lr] = f2b(v.x);
    t[lc + u * 4 + 1][lr] = f2b(v.y);
    t[lc + u * 4 + 2][lr] = f2b(v.z);
    t[lc + u * 4 + 3][lr] = f2b(v.w);
  }
  __syncthreads();
#pragma unroll
  for (int u = 0; u < 2; ++u) {
    bf16x8 o;
#pragma unroll
    for (int e = 0; e < 8; ++e) o[e] = (short)t[lr][lc + u * 8 + e];
    *(bf16x8*)&dst[(size_t)(c0 + lr) * R + r0 + lc + u * 8] = o;
  }
}

// ---------------- K1: qkv = x @ W_qkv + b. 128x128 tile, fused f32->bf16 cast of x.
// XCD-swizzled grid (768 blocks): XCD x owns m-tiles [x*8, x*8+8) x all 12 n-tiles,
// so the 2MB x-chunk is fetched once per XCD (fits 4MB L2) instead of 8x.
__global__ __launch_bounds__(256) void qkv_mfma(const float* __restrict__ x,
                                                const ushort* __restrict__ Wt,
                                                const float* __restrict__ bias,
                                                ushort* __restrict__ q,
                                                ushort* __restrict__ k,
                                                ushort* __restrict__ vt) {
  __shared__ ushort A[128][40];
  __shared__ ushort Bs[128][40];
  const int tid = threadIdx.x;
  const int bid = blockIdx.x;
  const int obid = (bid & 7) * 96 + (bid >> 3);  // bijective: 768 = 8 XCD x 96
  const int n0 = (obid % 12) * 128;
  const int m0 = (obid / 12) * 128;
  const int lane = tid & 63, wid = tid >> 6;
  const int wr = wid >> 1, wc = wid & 1;
  const int lr = lane & 15, g4 = lane >> 4;
  const int sr = tid >> 1, sco = (tid & 1) * 16;
  f32x4 acc[4][4] = {};
  for (int k0 = 0; k0 < 512; k0 += 32) {
    {
      const float4* xs = (const float4*)&x[(size_t)(m0 + sr) * 512 + k0 + sco];
      float4 v0 = xs[0], v1 = xs[1], v2 = xs[2], v3 = xs[3];
      bf16x8 p0, p1;
      p0[0] = (short)f2b(v0.x); p0[1] = (short)f2b(v0.y);
      p0[2] = (short)f2b(v0.z); p0[3] = (short)f2b(v0.w);
      p0[4] = (short)f2b(v1.x); p0[5] = (short)f2b(v1.y);
      p0[6] = (short)f2b(v1.z); p0[7] = (short)f2b(v1.w);
      p1[0] = (short)f2b(v2.x); p1[1] = (short)f2b(v2.y);
      p1[2] = (short)f2b(v2.z); p1[3] = (short)f2b(v2.w);
      p1[4] = (short)f2b(v3.x); p1[5] = (short)f2b(v3.y);
      p1[6] = (short)f2b(v3.z); p1[7] = (short)f2b(v3.w);
      *(bf16x8*)&A[sr][sco] = p0;
      *(bf16x8*)&A[sr][sco + 8] = p1;
    }
    {
      const bf16x8* wp = (const bf16x8*)&Wt[(size_t)(n0 + sr) * 512 + k0 + sco];
      *(bf16x8*)&Bs[sr][sco] = wp[0];
      *(bf16x8*)&Bs[sr][sco + 8] = wp[1];
    }
    __syncthreads();
    bf16x8 af[4], bf[4];
#pragma unroll
    for (int mr = 0; mr < 4; ++mr) af[mr] = *(bf16x8*)&A[wr * 64 + mr * 16 + lr][g4 * 8];
#pragma unroll
    for (int nr = 0; nr < 4; ++nr) bf[nr] = *(bf16x8*)&Bs[wc * 64 + nr * 16 + lr][g4 * 8];
#pragma unroll
    for (int mr = 0; mr < 4; ++mr)
#pragma unroll
      for (int nr = 0; nr < 4; ++nr) acc[mr][nr] = mfma16(af[mr], bf[nr], acc[mr][nr]);
    __syncthreads();
  }
  const int part = n0 >> 9;
#pragma unroll
  for (int mr = 0; mr < 4; ++mr)
#pragma unroll
    for (int nr = 0; nr < 4; ++nr) {
      const int n = n0 + wc * 64 + nr * 16 + lr;
      const int h = (n & 511) >> 6, d = n & 63;
      const float bb = bias[n];
#pragma unroll
      for (int r = 0; r < 4; ++r) {
        int token = m0 + wr * 64 + mr * 16 + g4 * 4 + r;
        int bi = token >> 10, ii = token & 1023;
        ushort valb = f2b(acc[mr][nr][r] + bb);
        if (part == 0)
          q[(((size_t)(bi * 8 + h) * 1024 + ii) * 64) + d] = valb;
        else if (part == 1)
          k[(((size_t)(bi * 8 + h) * 1024 + ii) * 64) + d] = valb;
        else
          vt[((size_t)(bi * 8 + h) * 64 + d) * 1024 + ii] = valb;
      }
    }
}

// ---------------- K2 (fused): S^T = mfma(K,Q) -> softmax (2-pass recompute) -> mix
//                  -> LN -> attn NT-write (f32x4) -> PV (O^T) -> pv (bf16)
// Best-measured structure (R11): QBLK=32, 256 blocks, 8 waves (wave h = head h),
// inline phase 0, 2 lgkm-only barriers/jt, XCD-swizzled (b == XCD), (512,2).
__global__ __launch_bounds__(512, 2) void attn_fused(const ushort* __restrict__ q,
                                                     const ushort* __restrict__ k,
                                                     const ushort* __restrict__ vt,
                                                     const float* __restrict__ rw,
                                                     const float* __restrict__ ln_g,
                                                     const float* __restrict__ ln_b,
                                                     float* __restrict__ attn,
                                                     ushort* __restrict__ pv) {
  __shared__ float PM[8][32][36];
  __shared__ float wsh[64];
  __shared__ float gsh[8], bsh[8];

  const int tid = threadIdx.x;
  const int lane = tid & 63;
  const int h = tid >> 6;
  const int obid = ((blockIdx.x & 7) << 5) + (blockIdx.x >> 3);  // b == XCD
  const int i0 = (obid & 31) * 32;
  const int b = obid >> 5;
  const int lr = lane & 15, g4 = lane >> 4;

  const int bh = b * 8 + h;
  const ushort* qh = q + ((size_t)bh * 1024 + i0) * 64;
  const ushort* kh = k + (size_t)bh * 65536;
  const ushort* vth = vt + (size_t)bh * 65536;

  if (tid < 64) wsh[tid] = rw[tid];
  if (tid < 8) { gsh[tid] = ln_g[tid]; bsh[tid] = ln_b[tid]; }

  // Q fragments (B-operand: col = i = lr, k-slice d = ks*32 + g4*8)
  bf16x8 qf[2][2];
#pragma unroll
  for (int ir = 0; ir < 2; ++ir)
#pragma unroll
    for (int ks = 0; ks < 2; ++ks)
      qf[ir][ks] = *(const bf16x8*)&qh[(size_t)(ir * 16 + lr) * 64 + ks * 32 + g4 * 8];

  // ---- Phase 0: denominators via S^T; lane accumulates its g4-group's j rows
  float psum[2] = {0.f, 0.f};
  {
    bf16x8 kc[4], kn[4];
#pragma unroll
    for (int jr = 0; jr < 2; ++jr)
#pragma unroll
      for (int ks = 0; ks < 2; ++ks)
        kc[jr * 2 + ks] = *(const bf16x8*)&kh[(size_t)(jr * 16 + lr) * 64 + ks * 32 + g4 * 8];
    for (int jt = 0; jt < 32; ++jt) {
      const int j0n = ((jt + 1) & 31) * 32;
#pragma unroll
      for (int jr = 0; jr < 2; ++jr)
#pragma unroll
        for (int ks = 0; ks < 2; ++ks)
          kn[jr * 2 + ks] =
              *(const bf16x8*)&kh[(size_t)(j0n + jr * 16 + lr) * 64 + ks * 32 + g4 * 8];
      f32x4 sa[2][2] = {};  // [jr][ir]
#pragma unroll
      for (int jr = 0; jr < 2; ++jr)
#pragma unroll
        for (int ir = 0; ir < 2; ++ir) {
          sa[jr][ir] = mfma16(kc[jr * 2 + 0], qf[ir][0], sa[jr][ir]);
          sa[jr][ir] = mfma16(kc[jr * 2 + 1], qf[ir][1], sa[jr][ir]);
        }
#pragma unroll
      for (int jr = 0; jr < 2; ++jr)
#pragma unroll
        for (int ir = 0; ir < 2; ++ir)
#pragma unroll
          for (int r = 0; r < 4; ++r) psum[ir] += __expf(sa[jr][ir][r] * SCALE_);
#pragma unroll
      for (int i = 0; i < 4; ++i) kc[i] = kn[i];
    }
  }
  float inv_[2];
#pragma unroll
  for (int ir = 0; ir < 2; ++ir) {
    float s = psum[ir];
    s += __shfl_xor(s, 16);
    s += __shfl_xor(s, 32);
    inv_[ir] = 1.0f / s;  // row sum for i = ir*16 + lr, in every lane
  }

  // ---- Phase 1
  f32x4 oaccT[4][2] = {};  // [dr][ic]: O^T
  const int pair = tid & 1, chunk = tid >> 1;
  const int m_ii = chunk >> 3, m_jj = (chunk & 7) * 4;
  const int k2base = pair * 4;

  bf16x8 kc[4], kn[4];
#pragma unroll
  for (int jr = 0; jr < 2; ++jr)
#pragma unroll
    for (int ks = 0; ks < 2; ++ks)
      kc[jr * 2 + ks] = *(const bf16x8*)&kh[(size_t)(jr * 16 + lr) * 64 + ks * 32 + g4 * 8];

  for (int jt = 0; jt < 32; ++jt) {
    const int j0 = jt * 32;
    const int j0n = ((jt + 1) & 31) * 32;
    // prefetch next K tile
#pragma unroll
    for (int jr = 0; jr < 2; ++jr)
#pragma unroll
      for (int ks = 0; ks < 2; ++ks)
        kn[jr * 2 + ks] =
            *(const bf16x8*)&kh[(size_t)(j0n + jr * 16 + lr) * 64 + ks * 32 + g4 * 8];

    // S^T recompute; P = exp*inv -> PM[h][i][j] with 4 consecutive j -> b128
    f32x4 sa[2][2] = {};  // [jr][ir]
#pragma unroll
    for (int jr = 0; jr < 2; ++jr)
#pragma unroll
      for (int ir = 0; ir < 2; ++ir) {
        sa[jr][ir] = mfma16(kc[jr * 2 + 0], qf[ir][0], sa[jr][ir]);
        sa[jr][ir] = mfma16(kc[jr * 2 + 1], qf[ir][1], sa[jr][ir]);
      }
#pragma unroll
    for (int jr = 0; jr < 2; ++jr)
#pragma unroll
      for (int ir = 0; ir < 2; ++ir) {
        f32x4 pw;
#pragma unroll
        for (int r = 0; r < 4; ++r) pw[r] = __expf(sa[jr][ir][r] * SCALE_) * inv_[ir];
        *(f32x4*)&PM[h][ir * 16 + lr][jr * 16 + g4 * 4] = pw;
      }

    // V loads for this iteration (pre-B1, consumed post-B2)
    bf16x8 vc[4];
#pragma unroll
    for (int dr = 0; dr < 4; ++dr)
      vc[dr] = *(const bf16x8*)&vth[(size_t)(dr * 16 + lr) * 1024 + j0 + g4 * 8];

    bar_lds();  // B1: all heads' P visible

    // mix + LN (float4, head-split across lane pairs), in-place PM update
    float4 ph[8];
#pragma unroll
    for (int h2 = 0; h2 < 8; ++h2) ph[h2] = *(const float4*)&PM[h2][m_ii][m_jj];
    float mixed[4][4];
#pragma unroll
    for (int k2l = 0; k2l < 4; ++k2l) {
      float a0 = 0.f, a1 = 0.f, a2 = 0.f, a3 = 0.f;
#pragma unroll
      for (int h2 = 0; h2 < 8; ++h2) {
        float w = wsh[h2 * 8 + k2base + k2l];
        a0 += ph[h2].x * w; a1 += ph[h2].y * w;
        a2 += ph[h2].z * w; a3 += ph[h2].w * w;
      }
      mixed[k2l][0] = a0; mixed[k2l][1] = a1; mixed[k2l][2] = a2; mixed[k2l][3] = a3;
    }
    float mu[4], rs_[4];
#pragma unroll
    for (int e = 0; e < 4; ++e) {
      float mp = mixed[0][e] + mixed[1][e] + mixed[2][e] + mixed[3][e];
      mu[e] = (mp + __shfl_xor(mp, 1)) * 0.125f;
    }
#pragma unroll
    for (int e = 0; e < 4; ++e) {
      float vp = 0.f;
#pragma unroll
      for (int k2l = 0; k2l < 4; ++k2l) {
        float d = mixed[k2l][e] - mu[e];
        vp += d * d;
      }
      float var = (vp + __shfl_xor(vp, 1)) * 0.125f;
      rs_[e] = rsqrtf(var + LN_EPS_);
    }
#pragma unroll
    for (int k2l = 0; k2l < 4; ++k2l) {
      int k2 = k2base + k2l;
      float g = gsh[k2], be = bsh[k2];
      f32x4 o;
      o[0] = (mixed[k2l][0] - mu[0]) * rs_[0] * g + be;
      o[1] = (mixed[k2l][1] - mu[1]) * rs_[1] * g + be;
      o[2] = (mixed[k2l][2] - mu[2]) * rs_[2] * g + be;
      o[3] = (mixed[k2l][3] - mu[3]) * rs_[3] * g + be;
      __builtin_nontemporal_store(
          o, (f32x4*)&attn[((size_t)(b * 8 + k2) << 20) + ((size_t)(i0 + m_ii) << 10) +
                           j0 + m_jj]);
      *(f32x4*)&PM[k2][m_ii][m_jj] = o;  // in-place
    }

    bar_lds();  // B2: LN'd PM visible

    // PV swapped: O^T += V^T(A) @ P^T(B); pab from PM rows via b128 + cvtpk
    bf16x8 pab[2];
#pragma unroll
    for (int ic = 0; ic < 2; ++ic) {
      const float* pr = &PM[h][ic * 16 + lr][g4 * 8];
      float4 p0 = *(const float4*)&pr[0];
      float4 p1 = *(const float4*)&pr[4];
      union { bf16x8 v; unsigned u[4]; } pk;
      pk.u[0] = cvtpk(p0.x, p0.y);
      pk.u[1] = cvtpk(p0.z, p0.w);
      pk.u[2] = cvtpk(p1.x, p1.y);
      pk.u[3] = cvtpk(p1.z, p1.w);
      pab[ic] = pk.v;
    }
#pragma unroll
    for (int dr = 0; dr < 4; ++dr) {
      oaccT[dr][0] = mfma16(vc[dr], pab[0], oaccT[dr][0]);
      oaccT[dr][1] = mfma16(vc[dr], pab[1], oaccT[dr][1]);
    }

#pragma unroll
    for (int i = 0; i < 4; ++i) kc[i] = kn[i];
  }

  // write pv (bf16, (b,h,i,d)); lane col i = lr, 4 consecutive d -> b64
  ushort* po = pv + ((size_t)bh * 1024 + i0) * 64;
#pragma unroll
  for (int ic = 0; ic < 2; ++ic)
#pragma unroll
    for (int dr = 0; dr < 4; ++dr) {
      union { ushort4 s; unsigned u[2]; } o;
      o.u[0] = cvtpk(oaccT[dr][ic][0], oaccT[dr][ic][1]);
      o.u[1] = cvtpk(oaccT[dr][ic][2], oaccT[dr][ic][3]);
      *(ushort4*)&po[(size_t)(ic * 16 + lr) * 64 + dr * 16 + g4 * 4] = o.s;
    }
}

// ---------------- K3: out = pv(b,n,(h d)) @ W_out + b_out. 128x128 tile.
// XCD-swizzled (256 blocks): XCD x owns m-tiles [x*8, x*8+8) x all 4 n-tiles.
__global__ __launch_bounds__(256) void out_mfma(const ushort* __restrict__ pvb,
                                                const ushort* __restrict__ Wt,
                                                const float* __restrict__ bias,
                                                float* __restrict__ out) {
  __shared__ ushort A[128][40];
  __shared__ ushort Bs[128][40];
  const int tid = threadIdx.x;
  const int bid = blockIdx.x;
  const int obid = ((bid & 7) << 5) + (bid >> 3);  // bijective: 256 = 8 x 32
  const int n0 = (obid & 3) * 128;
  const int m0 = (obid >> 2) * 128;
  const int lane = tid & 63, wid = tid >> 6;
  const int wr = wid >> 1, wc = wid & 1;
  const int lr = lane & 15, g4 = lane >> 4;
  const int sr = tid >> 1, sco = (tid & 1) * 16;
  f32x4 acc[4][4] = {};
  for (int k0 = 0; k0 < 512; k0 += 32) {
    {
      int token = m0 + sr;
      int bi = token >> 10, ii = token & 1023;
      int f = k0 + sco;
      int hh = f >> 6, d = f & 63;
      const bf16x8* src =
          (const bf16x8*)&pvb[(((size_t)(bi * 8 + hh)) * 1024 + ii) * 64 + d];
      *(bf16x8*)&A[sr][sco] = src[0];
      *(bf16x8*)&A[sr][sco + 8] = src[1];
    }
    {
      const bf16x8* wp = (const bf16x8*)&Wt[(size_t)(n0 + sr) * 512 + k0 + sco];
      *(bf16x8*)&Bs[sr][sco] = wp[0];
      *(bf16x8*)&Bs[sr][sco + 8] = wp[1];
    }
    __syncthreads();
    bf16x8 af[4], bf[4];
#pragma unroll
    for (int mr = 0; mr < 4; ++mr) af[mr] = *(bf16x8*)&A[wr * 64 + mr * 16 + lr][g4 * 8];
#pragma unroll
    for (int nr = 0; nr < 4; ++nr) bf[nr] = *(bf16x8*)&Bs[wc * 64 + nr * 16 + lr][g4 * 8];
#pragma unroll
    for (int mr = 0; mr < 4; ++mr)
#pragma unroll
      for (int nr = 0; nr < 4; ++nr) acc[mr][nr] = mfma16(af[mr], bf[nr], acc[mr][nr]);
    __syncthreads();
  }
#pragma unroll
  for (int mr = 0; mr < 4; ++mr)
#pragma unroll
    for (int nr = 0; nr < 4; ++nr) {
      const int n = n0 + wc * 64 + nr * 16 + lr;
      const float bb = bias[n];
#pragma unroll
      for (int r = 0; r < 4; ++r) {
        int token = m0 + wr * 64 + mr * 16 + g4 * 4 + r;
        out[(size_t)token * 512 + n] = acc[mr][nr][r] + bb;
      }
    }
}

extern "C" void kernel_launch(void* const* d_in, const int* in_sizes, int n_in,
                              void* d_out, int out_size, void* d_ws, size_t ws_size,
                              hipStream_t stream) {
  const float* x    = (const float*)d_in[0];
  const float* Wqkv = (const float*)d_in[1];
  const float* bqkv = (const float*)d_in[2];
  const float* rw   = (const float*)d_in[3];
  const float* lng  = (const float*)d_in[4];
  const float* lnb  = (const float*)d_in[5];
  const float* Wout = (const float*)d_in[6];
  const float* bout = (const float*)d_in[7];

  float* out  = (float*)d_out;
  float* attn = (float*)d_out + 4194304;

  // ws: q [0,8M), k [8,16M), vt [16,24M), pvb [24,32M), Wqkvt [32,33.5M), Woutt [33.5,34M)
  char* wsb = (char*)d_ws;
  ushort* q     = (ushort*)(wsb);
  ushort* k     = (ushort*)(wsb + (8u << 20));
  ushort* vt    = (ushort*)(wsb + (16u << 20));
  ushort* pvb   = (ushort*)(wsb + (24u << 20));
  ushort* Wqkvt = (ushort*)(wsb + (32u << 20));
  ushort* Woutt = (ushort*)(wsb + (33u << 20) + (1u << 19));

  cast_transpose2<<<dim3(256), 256, 0, stream>>>(Wqkv, Wqkvt, Wout, Woutt);
  qkv_mfma<<<dim3(768), 256, 0, stream>>>(x, Wqkvt, bqkv, q, k, vt);
  attn_fused<<<dim3(256), 512, 0, stream>>>(q, k, vt, rw, lng, lnb, attn, pvb);
  out_mfma<<<dim3(256), 256, 0, stream>>>(pvb, Woutt, bout, out);
}